// Round 1
// baseline (607.064 us; speedup 1.0000x reference)
//
#include <hip/hip_runtime.h>

#define NSEG 512
#define D 64

// Pass 1: per-segment sum of x (per-dim), sum of ||x||^2, and count.
// batch is sorted, so each wave takes a contiguous chunk of rows and
// accumulates in registers (lane i <-> dim i), flushing with atomics only
// when the segment id changes (~1 flush per wave).
__global__ void stats_kernel(const float* __restrict__ x, const int* __restrict__ batch,
                             float* __restrict__ sumx, float* __restrict__ sumsq,
                             float* __restrict__ cnt, int N) {
    const int lane   = threadIdx.x & 63;
    const int wid    = blockIdx.x * (blockDim.x >> 6) + (threadIdx.x >> 6);
    const int nwaves = gridDim.x * (blockDim.x >> 6);
    const int rpw    = (N + nwaves - 1) / nwaves;
    const int r0 = wid * rpw;
    const int r1 = min(r0 + rpw, N);
    if (r0 >= r1) return;

    float acc = 0.f, ssq = 0.f;
    int   nrun = 0;
    int   cur  = batch[r0];

    for (int r = r0; r < r1; ++r) {
        const int s = batch[r];           // wave-uniform load (all lanes same addr)
        if (s != cur) {                   // wave-uniform branch
            atomicAdd(&sumx[(size_t)cur * D + lane], acc);
            float t = ssq;
            #pragma unroll
            for (int off = 32; off; off >>= 1) t += __shfl_down(t, off);
            if (lane == 0) {
                atomicAdd(&sumsq[cur], t);
                atomicAdd(&cnt[cur], (float)nrun);
            }
            acc = 0.f; ssq = 0.f; nrun = 0; cur = s;
        }
        const float v = x[(size_t)r * D + lane];   // coalesced 256B/row per wave
        acc += v;
        ssq += v * v;
        ++nrun;
    }
    // final flush
    atomicAdd(&sumx[(size_t)cur * D + lane], acc);
    float t = ssq;
    #pragma unroll
    for (int off = 32; off; off >>= 1) t += __shfl_down(t, off);
    if (lane == 0) {
        atomicAdd(&sumsq[cur], t);
        atomicAdd(&cnt[cur], (float)nrun);
    }
}

// Pass 1.5: one wave per segment -> mean[s][d] and inv[s] = 1/sqrt(E[||x_c||^2]).
// Uses E[||x_c||^2] = sumsq/c - ||mean||^2 (exact algebra, fp32-safe here since
// ||mean||^2 ~ 0.03 << sumsq/c ~ 64).
__global__ void finalize_kernel(const float* __restrict__ sumx, const float* __restrict__ sumsq,
                                const float* __restrict__ cnt,
                                float* __restrict__ mean, float* __restrict__ inv) {
    const int lane = threadIdx.x & 63;
    const int s    = blockIdx.x * (blockDim.x >> 6) + (threadIdx.x >> 6);
    if (s >= NSEG) return;
    const float c  = cnt[s];
    const float cm = fmaxf(c, 1.f);
    const float m  = sumx[s * D + lane] / cm;
    mean[s * D + lane] = m;
    float mm = m * m;
    #pragma unroll
    for (int off = 32; off; off >>= 1) mm += __shfl_down(mm, off);
    if (lane == 0) {
        const float msq = fmaxf(sumsq[s] / cm - mm, 0.f);
        inv[s] = (msq > 0.f) ? (1.0f / sqrtf(msq)) : 0.f;
    }
}

// Pass 2: out = (x - mean[seg]) * inv[seg], float4-vectorized (16B/lane).
__global__ void apply_kernel(const float* __restrict__ x, const int* __restrict__ batch,
                             const float* __restrict__ mean, const float* __restrict__ inv,
                             float* __restrict__ out, int total /* = N*16 */) {
    const int gid = blockIdx.x * blockDim.x + threadIdx.x;
    if (gid >= total) return;
    const int row  = gid >> 4;
    const int quad = gid & 15;
    const int s    = batch[row];                         // broadcast within 16 lanes
    const float4 v = ((const float4*)x)[gid];
    const float4 m = ((const float4*)mean)[s * 16 + quad];  // L2-resident (128KB)
    const float iv = inv[s];                                // L2-resident (2KB)
    float4 o;
    o.x = (v.x - m.x) * iv;
    o.y = (v.y - m.y) * iv;
    o.z = (v.z - m.z) * iv;
    o.w = (v.w - m.w) * iv;
    ((float4*)out)[gid] = o;
}

extern "C" void kernel_launch(void* const* d_in, const int* in_sizes, int n_in,
                              void* d_out, int out_size, void* d_ws, size_t ws_size,
                              hipStream_t stream) {
    const float* x     = (const float*)d_in[0];
    const int*   batch = (const int*)d_in[1];
    float*       out   = (float*)d_out;
    const int N = in_sizes[0] / D;   // 1,000,000

    // Workspace layout (fp32 elems): sumx[NSEG*D] | sumsq[NSEG] | cnt[NSEG] | mean[NSEG*D] | inv[NSEG]
    float* sumx  = (float*)d_ws;
    float* sumsq = sumx + NSEG * D;
    float* cnt   = sumsq + NSEG;
    float* mean  = cnt + NSEG;
    float* inv   = mean + NSEG * D;

    // Zero only the accumulated stats (ws is re-poisoned 0xAA before every launch).
    hipMemsetAsync(d_ws, 0, (size_t)(NSEG * D + 2 * NSEG) * sizeof(float), stream);

    stats_kernel<<<1024, 256, 0, stream>>>(x, batch, sumx, sumsq, cnt, N);
    finalize_kernel<<<NSEG / 4, 256, 0, stream>>>(sumx, sumsq, cnt, mean, inv);

    const int total = N * (D / 4);   // one float4 per thread
    apply_kernel<<<(total + 255) / 256, 256, 0, stream>>>(x, batch, mean, inv, out, total);
}

// Round 3
// 471.443 us; speedup vs baseline: 1.2877x; 1.2877x over previous
//
#include <hip/hip_runtime.h>

#define NSEG 512
#define D 64

typedef float nfloat4 __attribute__((ext_vector_type(4)));  // for nontemporal builtin

// Pass 1: per-segment sum of x (per-dim), sum of ||x||^2, and count.
// batch is sorted int32. Each wave owns a contiguous row chunk; it binary-
// searches run boundaries ONCE per run (wave-uniform), then accumulates the
// run with a branch-free float4 loop (4 rows / 1 KiB per wave per iter).
// Lane layout inside the loop: sub = lane>>4 picks row r+sub within a 4-row
// group, dq = lane&15 picks dim-quad. Flush reduces subgroups via shfl_xor.
__global__ void stats_kernel(const float* __restrict__ x, const int* __restrict__ batch,
                             float* __restrict__ sumx, float* __restrict__ sumsq,
                             float* __restrict__ cnt, int N) {
    const int lane   = threadIdx.x & 63;
    const int wid    = blockIdx.x * (blockDim.x >> 6) + (threadIdx.x >> 6);
    const int nwaves = gridDim.x * (blockDim.x >> 6);
    const int rpw    = (N + nwaves - 1) / nwaves;
    int r        = wid * rpw;
    const int r1 = min(r + rpw, N);
    if (r >= r1) return;

    const int sub = lane >> 4;   // row subgroup 0..3
    const int dq  = lane & 15;   // dim quad 0..15

    while (r < r1) {
        const int s = batch[r];                 // wave-uniform
        // binary search: first index in (r, r1) with batch != s
        int lo = r + 1, hi = r1;
        while (lo < hi) {
            const int mid = (lo + hi) >> 1;
            if (batch[mid] == s) lo = mid + 1; else hi = mid;
        }
        const int e     = lo;
        const int nrows = e - r;
        const int nfull = nrows >> 2;           // 4-row groups

        float4 acc = make_float4(0.f, 0.f, 0.f, 0.f);
        float  ssq = 0.f;

        // branch-free bulk: lane L reads float4 #(r*16 + i*64 + L)
        const float4* p = (const float4*)(x) + (size_t)r * 16 + lane;
        #pragma unroll 4
        for (int i = 0; i < nfull; ++i) {
            const float4 v = p[(size_t)i * 64];
            acc.x += v.x; acc.y += v.y; acc.z += v.z; acc.w += v.w;
            ssq = fmaf(v.x, v.x, ssq); ssq = fmaf(v.y, v.y, ssq);
            ssq = fmaf(v.z, v.z, ssq); ssq = fmaf(v.w, v.w, ssq);
        }
        const int rem = nrows & 3;
        if (rem) {                              // tail rows (<4), masked by subgroup
            const int rr = r + (nfull << 2) + sub;
            if (sub < rem) {
                const float4 v = *((const float4*)(x) + (size_t)rr * 16 + dq);
                acc.x += v.x; acc.y += v.y; acc.z += v.z; acc.w += v.w;
                ssq = fmaf(v.x, v.x, ssq); ssq = fmaf(v.y, v.y, ssq);
                ssq = fmaf(v.z, v.z, ssq); ssq = fmaf(v.w, v.w, ssq);
            }
        }

        // reduce the 4 row-subgroups: lanes L, L^16, L^32(,^48) hold same dims
        acc.x += __shfl_xor(acc.x, 16); acc.x += __shfl_xor(acc.x, 32);
        acc.y += __shfl_xor(acc.y, 16); acc.y += __shfl_xor(acc.y, 32);
        acc.z += __shfl_xor(acc.z, 16); acc.z += __shfl_xor(acc.z, 32);
        acc.w += __shfl_xor(acc.w, 16); acc.w += __shfl_xor(acc.w, 32);
        if (sub == 0) {                         // lanes 0..15 flush 4 dims each
            float* dst = &sumx[(size_t)s * D + dq * 4];
            atomicAdd(dst + 0, acc.x);
            atomicAdd(dst + 1, acc.y);
            atomicAdd(dst + 2, acc.z);
            atomicAdd(dst + 3, acc.w);
        }
        // full-wave reduce for ssq
        float t = ssq;
        #pragma unroll
        for (int off = 1; off < 64; off <<= 1) t += __shfl_xor(t, off);
        if (lane == 0) {
            atomicAdd(&sumsq[s], t);
            atomicAdd(&cnt[s], (float)nrows);
        }
        r = e;
    }
}

// Pass 1.5: one wave per segment -> mean[s][d], inv[s] = 1/sqrt(E[||x_c||^2]).
// E[||x_c||^2] = sumsq/c - ||mean||^2 (fp32-safe: ||mean||^2 << sumsq/c).
__global__ void finalize_kernel(const float* __restrict__ sumx, const float* __restrict__ sumsq,
                                const float* __restrict__ cnt,
                                float* __restrict__ mean, float* __restrict__ inv) {
    const int lane = threadIdx.x & 63;
    const int s    = blockIdx.x * (blockDim.x >> 6) + (threadIdx.x >> 6);
    if (s >= NSEG) return;
    const float c  = cnt[s];
    const float cm = fmaxf(c, 1.f);
    const float m  = sumx[s * D + lane] / cm;
    mean[s * D + lane] = m;
    float mm = m * m;
    #pragma unroll
    for (int off = 1; off < 64; off <<= 1) mm += __shfl_xor(mm, off);
    if (lane == 0) {
        const float msq = fmaxf(sumsq[s] / cm - mm, 0.f);
        inv[s] = (msq > 0.f) ? (1.0f / sqrtf(msq)) : 0.f;
    }
}

// Pass 2: out = (x - mean[seg]) * inv[seg], float4 per thread.
// Nontemporal store: out is write-once; keep L2/L3 capacity for x.
__global__ void apply_kernel(const float* __restrict__ x, const int* __restrict__ batch,
                             const float* __restrict__ mean, const float* __restrict__ inv,
                             float* __restrict__ out, int total /* = N*16 */) {
    const int gid = blockIdx.x * blockDim.x + threadIdx.x;
    if (gid >= total) return;
    const int row  = gid >> 4;
    const int quad = gid & 15;
    const int s    = batch[row];
    const float4 v = ((const float4*)x)[gid];
    const float4 m = ((const float4*)mean)[s * 16 + quad];   // L2-resident (128KB)
    const float iv = inv[s];                                 // L2-resident (2KB)
    nfloat4 o;
    o.x = (v.x - m.x) * iv;
    o.y = (v.y - m.y) * iv;
    o.z = (v.z - m.z) * iv;
    o.w = (v.w - m.w) * iv;
    __builtin_nontemporal_store(o, (nfloat4*)out + gid);
}

extern "C" void kernel_launch(void* const* d_in, const int* in_sizes, int n_in,
                              void* d_out, int out_size, void* d_ws, size_t ws_size,
                              hipStream_t stream) {
    const float* x     = (const float*)d_in[0];
    const int*   batch = (const int*)d_in[1];
    float*       out   = (float*)d_out;
    const int N = in_sizes[0] / D;   // 1,000,000

    // ws layout (fp32): sumx[NSEG*D] | sumsq[NSEG] | cnt[NSEG] | mean[NSEG*D] | inv[NSEG]
    float* sumx  = (float*)d_ws;
    float* sumsq = sumx + NSEG * D;
    float* cnt   = sumsq + NSEG;
    float* mean  = cnt + NSEG;
    float* inv   = mean + NSEG * D;

    (void)hipMemsetAsync(d_ws, 0, (size_t)(NSEG * D + 2 * NSEG) * sizeof(float), stream);

    // 2048 blocks x 4 waves = 8192 waves -> 32 waves/CU capacity, ~122 rows/wave
    stats_kernel<<<2048, 256, 0, stream>>>(x, batch, sumx, sumsq, cnt, N);
    finalize_kernel<<<NSEG / 4, 256, 0, stream>>>(sumx, sumsq, cnt, mean, inv);

    const int total = N * (D / 4);
    apply_kernel<<<(total + 255) / 256, 256, 0, stream>>>(x, batch, mean, inv, out, total);
}